// Round 1
// baseline (858.027 us; speedup 1.0000x reference)
//
#include <hip/hip_runtime.h>
#include <hip/hip_fp16.h>
#include <stdint.h>

#define B_ROWS 4096
#define N_PAT  8192
#define N_NEU  1024

typedef _Float16 f16x8 __attribute__((ext_vector_type(8)));
typedef _Float16 f16x4 __attribute__((ext_vector_type(4)));
typedef float    f32x4 __attribute__((ext_vector_type(4)));

// ---------------- fp32 -> fp16 elementwise convert (vectorized) ----------------
__global__ __launch_bounds__(256) void convert_f32_f16(
    const float* __restrict__ in, _Float16* __restrict__ out, int n4) {
  int idx    = blockIdx.x * 256 + threadIdx.x;
  int stride = gridDim.x * 256;
  for (int i = idx; i < n4; i += stride) {
    float4 v = reinterpret_cast<const float4*>(in)[i];
    f16x4 h  = { (_Float16)v.x, (_Float16)v.y, (_Float16)v.z, (_Float16)v.w };
    reinterpret_cast<f16x4*>(out)[i] = h;
  }
}

// ---------------- fp32 [rows][cols] -> fp16 transpose [cols][rows] ----------------
__global__ __launch_bounds__(256) void transpose_f32_f16(
    const float* __restrict__ in, _Float16* __restrict__ out, int rows, int cols) {
  __shared__ float tile[32][33];
  int c0 = blockIdx.x * 32, r0 = blockIdx.y * 32;
  int tx = threadIdx.x, ty = threadIdx.y;  // 32 x 8
  #pragma unroll
  for (int i = 0; i < 32; i += 8)
    tile[ty + i][tx] = in[(size_t)(r0 + ty + i) * cols + c0 + tx];
  __syncthreads();
  #pragma unroll
  for (int i = 0; i < 32; i += 8)
    out[(size_t)(c0 + ty + i) * rows + r0 + tx] = (_Float16)tile[tx][ty + i];
}

// ---------------- async global->LDS, 16B per lane, wave-uniform LDS base ----------------
__device__ __forceinline__ void gload_lds16(const _Float16* g, _Float16* l) {
  __builtin_amdgcn_global_load_lds(
      (const __attribute__((address_space(1))) uint32_t*)g,
      (__attribute__((address_space(3))) uint32_t*)l, 16, 0, 0);
}

// ---------------- C[M,N] = A[M,K] @ Bt[N,K]^T ----------------
// fp16 inputs, fp32 MFMA accumulation, OUT_T output. 128x128 tile, BK=32,
// 4 waves in 2x2, each wave owns a 64x64 sub-tile (4x4 fragments of 16x16x32).
template <typename OUT_T>
__global__ __launch_bounds__(256) void gemm_bt(
    const _Float16* __restrict__ A, const _Float16* __restrict__ Bt,
    OUT_T* __restrict__ C, int M, int N, int K) {
  __shared__ _Float16 As[128 * 32];
  __shared__ _Float16 Bs[128 * 32];
  const int t    = threadIdx.x;
  const int lane = t & 63;
  const int w    = t >> 6;          // wave id 0..3
  const int wr   = w >> 1;          // wave row 0..1
  const int wc   = w & 1;           // wave col 0..1
  const int m0   = blockIdx.x * 128;
  const int n0   = blockIdx.y * 128;

  // Staging: 2 issues per matrix per K-step. Issue j covers rows j*64 + w*16 + (lane>>2),
  // cols (lane&3)*8 .. +7. LDS dest is linear (wave-uniform base + lane*16).
  const int srow = w * 16 + (lane >> 2);
  const int scol = (lane & 3) * 8;
  const _Float16* gA = A  + (size_t)(m0 + srow) * K + scol;
  const _Float16* gB = Bt + (size_t)(n0 + srow) * K + scol;
  const size_t jump = (size_t)64 * K;  // issue 1 is 64 rows below
  _Float16* lA0 = As + w * 512;
  _Float16* lA1 = As + (4 + w) * 512;
  _Float16* lB0 = Bs + w * 512;
  _Float16* lB1 = Bs + (4 + w) * 512;

  const int lrow = lane & 15;  // fragment row (A) / col (B)
  const int kg   = lane >> 4;  // k-group 0..3, 8 elems each

  f32x4 acc[4][4] = {};

  for (int kt = 0; kt < K; kt += 32) {
    gload_lds16(gA + kt, lA0);
    gload_lds16(gA + jump + kt, lA1);
    gload_lds16(gB + kt, lB0);
    gload_lds16(gB + jump + kt, lB1);
    __syncthreads();  // compiler emits vmcnt(0) drain before s_barrier

    f16x8 af[4], bf[4];
    #pragma unroll
    for (int mi = 0; mi < 4; ++mi)
      af[mi] = *reinterpret_cast<const f16x8*>(&As[(wr * 64 + mi * 16 + lrow) * 32 + kg * 8]);
    #pragma unroll
    for (int ni = 0; ni < 4; ++ni)
      bf[ni] = *reinterpret_cast<const f16x8*>(&Bs[(wc * 64 + ni * 16 + lrow) * 32 + kg * 8]);
    #pragma unroll
    for (int mi = 0; mi < 4; ++mi) {
      #pragma unroll
      for (int ni = 0; ni < 4; ++ni)
        acc[mi][ni] = __builtin_amdgcn_mfma_f32_16x16x32_f16(af[mi], bf[ni], acc[mi][ni], 0, 0, 0);
    }
    __syncthreads();
  }

  // C/D layout: col = lane&15, row = (lane>>4)*4 + reg  (dtype-independent, m89/m101)
  const int crow = (lane >> 4) * 4;
  const int ccol = lane & 15;
  #pragma unroll
  for (int mi = 0; mi < 4; ++mi) {
    #pragma unroll
    for (int ni = 0; ni < 4; ++ni) {
      #pragma unroll
      for (int r = 0; r < 4; ++r) {
        int row = m0 + wr * 64 + mi * 16 + crow + r;
        int col = n0 + wc * 64 + ni * 16 + ccol;
        C[(size_t)row * N + col] = (OUT_T)acc[mi][ni][r];
      }
    }
  }
}

// ---------------- in-place row softmax over N=8192 fp16 scores ----------------
// One 256-thread block per row; the full row lives in registers (32 f32/thread).
__global__ __launch_bounds__(256) void softmax_rows(_Float16* __restrict__ S, int N) {
  const int t = threadIdx.x;
  f16x8* pv = reinterpret_cast<f16x8*>(S + (size_t)blockIdx.x * N);
  float v[32];
  float m = -3.0e38f;
  #pragma unroll
  for (int i = 0; i < 4; ++i) {
    f16x8 h = pv[i * 256 + t];
    #pragma unroll
    for (int e = 0; e < 8; ++e) {
      float f = (float)h[e];
      v[i * 8 + e] = f;
      m = fmaxf(m, f);
    }
  }
  #pragma unroll
  for (int o = 32; o; o >>= 1) m = fmaxf(m, __shfl_xor(m, o));
  __shared__ float redm[4];
  if ((t & 63) == 0) redm[t >> 6] = m;
  __syncthreads();
  m = fmaxf(fmaxf(redm[0], redm[1]), fmaxf(redm[2], redm[3]));

  float s = 0.f;
  #pragma unroll
  for (int i = 0; i < 32; ++i) { v[i] = __expf(v[i] - m); s += v[i]; }
  #pragma unroll
  for (int o = 32; o; o >>= 1) s += __shfl_xor(s, o);
  __shared__ float reds[4];
  if ((t & 63) == 0) reds[t >> 6] = s;
  __syncthreads();
  s = reds[0] + reds[1] + reds[2] + reds[3];
  const float inv = 1.0f / s;

  #pragma unroll
  for (int i = 0; i < 4; ++i) {
    f16x8 h;
    #pragma unroll
    for (int e = 0; e < 8; ++e) h[e] = (_Float16)(v[i * 8 + e] * inv);
    pv[i * 256 + t] = h;
  }
}

extern "C" void kernel_launch(void* const* d_in, const int* in_sizes, int n_in,
                              void* d_out, int out_size, void* d_ws, size_t ws_size,
                              hipStream_t stream) {
  const float* x        = (const float*)d_in[0];
  const float* patterns = (const float*)d_in[1];
  float* out            = (float*)d_out;
  char* ws = (char*)d_ws;

  // workspace layout (104 MB total):
  _Float16* Xb  = (_Float16*)(ws);                         //  8 MB [4096][1024]
  _Float16* Pb  = (_Float16*)(ws + ((size_t)8  << 20));    // 16 MB [8192][1024]
  _Float16* PbT = (_Float16*)(ws + ((size_t)24 << 20));    // 16 MB [1024][8192]
  _Float16* S   = (_Float16*)(ws + ((size_t)40 << 20));    // 64 MB [4096][8192] scores/probs in-place

  convert_f32_f16<<<dim3(1024), dim3(256), 0, stream>>>(x, Xb, (B_ROWS * N_NEU) / 4);
  convert_f32_f16<<<dim3(2048), dim3(256), 0, stream>>>(patterns, Pb, (N_PAT * N_NEU) / 4);
  transpose_f32_f16<<<dim3(N_NEU / 32, N_PAT / 32), dim3(32, 8), 0, stream>>>(patterns, PbT, N_PAT, N_NEU);

  for (int it = 0; it < 3; ++it) {
    // scores = Xb @ Pb^T  (TEMPERATURE == 1.0, no scaling needed)
    gemm_bt<_Float16><<<dim3(B_ROWS / 128, N_PAT / 128), dim3(256), 0, stream>>>(
        Xb, Pb, S, B_ROWS, N_PAT, N_NEU);
    softmax_rows<<<dim3(B_ROWS), dim3(256), 0, stream>>>(S, N_PAT);
    // new_x = probs @ P  ==  probs @ (PbT)^T
    if (it < 2) {
      gemm_bt<_Float16><<<dim3(B_ROWS / 128, N_NEU / 128), dim3(256), 0, stream>>>(
          S, PbT, Xb, B_ROWS, N_NEU, N_PAT);
    } else {
      gemm_bt<float><<<dim3(B_ROWS / 128, N_NEU / 128), dim3(256), 0, stream>>>(
          S, PbT, out, B_ROWS, N_NEU, N_PAT);
    }
  }
}

// Round 2
// 656.466 us; speedup vs baseline: 1.3070x; 1.3070x over previous
//
#include <hip/hip_runtime.h>
#include <hip/hip_fp16.h>
#include <stdint.h>

#define B_ROWS 4096
#define N_PAT  8192
#define N_NEU  1024

typedef _Float16 f16x8 __attribute__((ext_vector_type(8)));
typedef _Float16 f16x4 __attribute__((ext_vector_type(4)));
typedef float    f32x4 __attribute__((ext_vector_type(4)));

// ---------------- fp32 -> fp16 elementwise convert (vectorized) ----------------
__global__ __launch_bounds__(256) void convert_f32_f16(
    const float* __restrict__ in, _Float16* __restrict__ out, int n4) {
  int idx    = blockIdx.x * 256 + threadIdx.x;
  int stride = gridDim.x * 256;
  for (int i = idx; i < n4; i += stride) {
    float4 v = reinterpret_cast<const float4*>(in)[i];
    f16x4 h  = { (_Float16)v.x, (_Float16)v.y, (_Float16)v.z, (_Float16)v.w };
    reinterpret_cast<f16x4*>(out)[i] = h;
  }
}

// ---------------- fp32 [rows][cols] -> fp16 transpose [cols][rows] ----------------
__global__ __launch_bounds__(256) void transpose_f32_f16(
    const float* __restrict__ in, _Float16* __restrict__ out, int rows, int cols) {
  __shared__ float tile[32][33];
  int c0 = blockIdx.x * 32, r0 = blockIdx.y * 32;
  int tx = threadIdx.x, ty = threadIdx.y;  // 32 x 8
  #pragma unroll
  for (int i = 0; i < 32; i += 8)
    tile[ty + i][tx] = in[(size_t)(r0 + ty + i) * cols + c0 + tx];
  __syncthreads();
  #pragma unroll
  for (int i = 0; i < 32; i += 8)
    out[(size_t)(c0 + ty + i) * rows + r0 + tx] = (_Float16)tile[tx][ty + i];
}

// ---------------- async global->LDS, 16B per lane, wave-uniform LDS base ----------------
__device__ __forceinline__ void gload_lds16(const _Float16* g, _Float16* l) {
  __builtin_amdgcn_global_load_lds(
      (const __attribute__((address_space(1))) uint32_t*)g,
      (__attribute__((address_space(3))) uint32_t*)l, 16, 0, 0);
}

// ---------------- C[M,N] = A[M,K] @ Bt[N,K]^T ----------------
// fp16 inputs, fp32 MFMA accumulation, OUT_T output. 128x128 tile, BK=32,
// 4 waves in 2x2, each wave owns a 64x64 sub-tile (4x4 fragments of 16x16x32).
// Single-buffered; good when >=4 blocks/CU are resident (used for GEMM1).
template <typename OUT_T>
__global__ __launch_bounds__(256) void gemm_bt(
    const _Float16* __restrict__ A, const _Float16* __restrict__ Bt,
    OUT_T* __restrict__ C, int M, int N, int K) {
  __shared__ _Float16 As[128 * 32];
  __shared__ _Float16 Bs[128 * 32];
  const int t    = threadIdx.x;
  const int lane = t & 63;
  const int w    = t >> 6;
  const int wr   = w >> 1;
  const int wc   = w & 1;
  const int m0   = blockIdx.x * 128;
  const int n0   = blockIdx.y * 128;

  const int srow = w * 16 + (lane >> 2);
  const int scol = (lane & 3) * 8;
  const _Float16* gA = A  + (size_t)(m0 + srow) * K + scol;
  const _Float16* gB = Bt + (size_t)(n0 + srow) * K + scol;
  const size_t jump = (size_t)64 * K;
  _Float16* lA0 = As + w * 512;
  _Float16* lA1 = As + (4 + w) * 512;
  _Float16* lB0 = Bs + w * 512;
  _Float16* lB1 = Bs + (4 + w) * 512;

  const int lrow = lane & 15;
  const int kg   = lane >> 4;

  f32x4 acc[4][4] = {};

  for (int kt = 0; kt < K; kt += 32) {
    gload_lds16(gA + kt, lA0);
    gload_lds16(gA + jump + kt, lA1);
    gload_lds16(gB + kt, lB0);
    gload_lds16(gB + jump + kt, lB1);
    __syncthreads();

    f16x8 af[4], bf[4];
    #pragma unroll
    for (int mi = 0; mi < 4; ++mi)
      af[mi] = *reinterpret_cast<const f16x8*>(&As[(wr * 64 + mi * 16 + lrow) * 32 + kg * 8]);
    #pragma unroll
    for (int ni = 0; ni < 4; ++ni)
      bf[ni] = *reinterpret_cast<const f16x8*>(&Bs[(wc * 64 + ni * 16 + lrow) * 32 + kg * 8]);
    #pragma unroll
    for (int mi = 0; mi < 4; ++mi) {
      #pragma unroll
      for (int ni = 0; ni < 4; ++ni)
        acc[mi][ni] = __builtin_amdgcn_mfma_f32_16x16x32_f16(af[mi], bf[ni], acc[mi][ni], 0, 0, 0);
    }
    __syncthreads();
  }

  const int crow = (lane >> 4) * 4;
  const int ccol = lane & 15;
  #pragma unroll
  for (int mi = 0; mi < 4; ++mi) {
    #pragma unroll
    for (int ni = 0; ni < 4; ++ni) {
      #pragma unroll
      for (int r = 0; r < 4; ++r) {
        int row = m0 + wr * 64 + mi * 16 + crow + r;
        int col = n0 + wc * 64 + ni * 16 + ccol;
        C[(size_t)row * N + col] = (OUT_T)acc[mi][ni][r];
      }
    }
  }
}

// ---------------- split-K GEMM2: Cp[z][M][N] += A[M,k0:k1] @ Bt[N,k0:k1]^T ----------------
// Double-buffered LDS, issue-early staging (T3 minimum 2-phase): STAGE(t+1) goes
// out BEFORE the ds_read+MFMA of tile t, so the vmcnt(0) drain at the barrier
// lands ~400 cyc after issue. fp32 partial output per K-split (blockIdx.z).
__global__ __launch_bounds__(256, 4) void gemm_bt_splitk(
    const _Float16* __restrict__ A, const _Float16* __restrict__ Bt,
    float* __restrict__ Cp, int M, int N, int K, int KS) {
  __shared__ _Float16 As[2][128 * 32];
  __shared__ _Float16 Bs[2][128 * 32];
  const int t    = threadIdx.x;
  const int lane = t & 63;
  const int w    = t >> 6;
  const int wr   = w >> 1;
  const int wc   = w & 1;
  const int m0   = blockIdx.x * 128;
  const int n0   = blockIdx.y * 128;
  const int k0   = blockIdx.z * KS;

  const int srow = w * 16 + (lane >> 2);
  const int scol = (lane & 3) * 8;
  const _Float16* gA = A  + (size_t)(m0 + srow) * K + scol + k0;
  const _Float16* gB = Bt + (size_t)(n0 + srow) * K + scol + k0;
  const size_t jump = (size_t)64 * K;

  const int lrow = lane & 15;
  const int kg   = lane >> 4;
  const int nt   = KS / 32;

  f32x4 acc[4][4] = {};

  // prologue: stage tile 0 into buffer 0
  {
    _Float16* lA = &As[0][w * 512];
    _Float16* lB = &Bs[0][w * 512];
    gload_lds16(gA, lA);
    gload_lds16(gA + jump, lA + 2048);
    gload_lds16(gB, lB);
    gload_lds16(gB + jump, lB + 2048);
  }
  __syncthreads();

  for (int it = 0; it < nt; ++it) {
    const int cur = it & 1;
    // issue next tile's loads early (into the other buffer)
    if (it + 1 < nt) {
      const int kt = (it + 1) * 32;
      _Float16* lA = &As[cur ^ 1][w * 512];
      _Float16* lB = &Bs[cur ^ 1][w * 512];
      gload_lds16(gA + kt, lA);
      gload_lds16(gA + jump + kt, lA + 2048);
      gload_lds16(gB + kt, lB);
      gload_lds16(gB + jump + kt, lB + 2048);
    }

    f16x8 af[4], bf[4];
    #pragma unroll
    for (int mi = 0; mi < 4; ++mi)
      af[mi] = *reinterpret_cast<const f16x8*>(&As[cur][(wr * 64 + mi * 16 + lrow) * 32 + kg * 8]);
    #pragma unroll
    for (int ni = 0; ni < 4; ++ni)
      bf[ni] = *reinterpret_cast<const f16x8*>(&Bs[cur][(wc * 64 + ni * 16 + lrow) * 32 + kg * 8]);
    #pragma unroll
    for (int mi = 0; mi < 4; ++mi) {
      #pragma unroll
      for (int ni = 0; ni < 4; ++ni)
        acc[mi][ni] = __builtin_amdgcn_mfma_f32_16x16x32_f16(af[mi], bf[ni], acc[mi][ni], 0, 0, 0);
    }
    __syncthreads();  // drains next-tile vmcnt + guards buffer reuse
  }

  float* Cz = Cp + (size_t)blockIdx.z * M * N;
  const int crow = (lane >> 4) * 4;
  const int ccol = lane & 15;
  #pragma unroll
  for (int mi = 0; mi < 4; ++mi) {
    #pragma unroll
    for (int ni = 0; ni < 4; ++ni) {
      #pragma unroll
      for (int r = 0; r < 4; ++r) {
        int row = m0 + wr * 64 + mi * 16 + crow + r;
        int col = n0 + wc * 64 + ni * 16 + ccol;
        Cz[(size_t)row * N + col] = acc[mi][ni][r];
      }
    }
  }
}

// ---------------- sum SPLIT fp32 partials -> OUT_T ----------------
template <typename OUT_T, int SPLIT>
__global__ __launch_bounds__(256) void reduce_partials(
    const float* __restrict__ Cp, OUT_T* __restrict__ out, int n4, int stride4) {
  int idx    = blockIdx.x * 256 + threadIdx.x;
  int stride = gridDim.x * 256;
  for (int i = idx; i < n4; i += stride) {
    float4 a = reinterpret_cast<const float4*>(Cp)[i];
    #pragma unroll
    for (int s = 1; s < SPLIT; ++s) {
      float4 b = reinterpret_cast<const float4*>(Cp)[(size_t)s * stride4 + i];
      a.x += b.x; a.y += b.y; a.z += b.z; a.w += b.w;
    }
    if constexpr (sizeof(OUT_T) == 2) {
      f16x4 h = { (_Float16)a.x, (_Float16)a.y, (_Float16)a.z, (_Float16)a.w };
      reinterpret_cast<f16x4*>(out)[i] = h;
    } else {
      reinterpret_cast<float4*>(out)[i] = a;
    }
  }
}

// ---------------- in-place row softmax over N=8192 fp16 scores ----------------
__global__ __launch_bounds__(256) void softmax_rows(_Float16* __restrict__ S, int N) {
  const int t = threadIdx.x;
  f16x8* pv = reinterpret_cast<f16x8*>(S + (size_t)blockIdx.x * N);
  float v[32];
  float m = -3.0e38f;
  #pragma unroll
  for (int i = 0; i < 4; ++i) {
    f16x8 h = pv[i * 256 + t];
    #pragma unroll
    for (int e = 0; e < 8; ++e) {
      float f = (float)h[e];
      v[i * 8 + e] = f;
      m = fmaxf(m, f);
    }
  }
  #pragma unroll
  for (int o = 32; o; o >>= 1) m = fmaxf(m, __shfl_xor(m, o));
  __shared__ float redm[4];
  if ((t & 63) == 0) redm[t >> 6] = m;
  __syncthreads();
  m = fmaxf(fmaxf(redm[0], redm[1]), fmaxf(redm[2], redm[3]));

  float s = 0.f;
  #pragma unroll
  for (int i = 0; i < 32; ++i) { v[i] = __expf(v[i] - m); s += v[i]; }
  #pragma unroll
  for (int o = 32; o; o >>= 1) s += __shfl_xor(s, o);
  __shared__ float reds[4];
  if ((t & 63) == 0) reds[t >> 6] = s;
  __syncthreads();
  s = reds[0] + reds[1] + reds[2] + reds[3];
  const float inv = 1.0f / s;

  #pragma unroll
  for (int i = 0; i < 4; ++i) {
    f16x8 h;
    #pragma unroll
    for (int e = 0; e < 8; ++e) h[e] = (_Float16)(v[i * 8 + e] * inv);
    pv[i * 256 + t] = h;
  }
}

extern "C" void kernel_launch(void* const* d_in, const int* in_sizes, int n_in,
                              void* d_out, int out_size, void* d_ws, size_t ws_size,
                              hipStream_t stream) {
  const float* x        = (const float*)d_in[0];
  const float* patterns = (const float*)d_in[1];
  float* out            = (float*)d_out;
  char* ws = (char*)d_ws;

  // workspace layout:
  _Float16* Xb   = (_Float16*)(ws);                          //   8 MB [4096][1024]
  _Float16* Pb   = (_Float16*)(ws + ((size_t)8  << 20));     //  16 MB [8192][1024]
  _Float16* PbT  = (_Float16*)(ws + ((size_t)24 << 20));     //  16 MB [1024][8192]
  _Float16* S    = (_Float16*)(ws + ((size_t)40 << 20));     //  64 MB [4096][8192]
  float*    part = (float*)   (ws + ((size_t)104 << 20));    //  split x 16 MB fp32 partials

  const size_t base = (size_t)104 << 20;
  const int split = (ws_size >= base + ((size_t)64 << 20)) ? 4
                  : (ws_size >= base + ((size_t)32 << 20)) ? 2 : 1;

  convert_f32_f16<<<dim3(1024), dim3(256), 0, stream>>>(x, Xb, (B_ROWS * N_NEU) / 4);
  convert_f32_f16<<<dim3(2048), dim3(256), 0, stream>>>(patterns, Pb, (N_PAT * N_NEU) / 4);
  transpose_f32_f16<<<dim3(N_NEU / 32, N_PAT / 32), dim3(32, 8), 0, stream>>>(patterns, PbT, N_PAT, N_NEU);

  const int n4 = (B_ROWS * N_NEU) / 4;      // reduce vec4 count
  const int stride4 = n4;                    // one partial = M*N/4 float4s

  for (int it = 0; it < 3; ++it) {
    // scores = Xb @ Pb^T  (TEMPERATURE == 1.0)
    gemm_bt<_Float16><<<dim3(B_ROWS / 128, N_PAT / 128), dim3(256), 0, stream>>>(
        Xb, Pb, S, B_ROWS, N_PAT, N_NEU);
    softmax_rows<<<dim3(B_ROWS), dim3(256), 0, stream>>>(S, N_PAT);

    // new_x = probs @ P == probs @ (PbT)^T   (M=4096, N=1024, K=8192)
    if (split > 1) {
      gemm_bt_splitk<<<dim3(B_ROWS / 128, N_NEU / 128, split), dim3(256), 0, stream>>>(
          S, PbT, part, B_ROWS, N_NEU, N_PAT, N_PAT / split);
      if (it < 2) {
        if (split == 4)
          reduce_partials<_Float16, 4><<<dim3(2048), dim3(256), 0, stream>>>(part, Xb, n4, stride4);
        else
          reduce_partials<_Float16, 2><<<dim3(2048), dim3(256), 0, stream>>>(part, Xb, n4, stride4);
      } else {
        if (split == 4)
          reduce_partials<float, 4><<<dim3(2048), dim3(256), 0, stream>>>(part, out, n4, stride4);
        else
          reduce_partials<float, 2><<<dim3(2048), dim3(256), 0, stream>>>(part, out, n4, stride4);
      }
    } else {
      if (it < 2)
        gemm_bt<_Float16><<<dim3(B_ROWS / 128, N_NEU / 128), dim3(256), 0, stream>>>(
            S, PbT, Xb, B_ROWS, N_NEU, N_PAT);
      else
        gemm_bt<float><<<dim3(B_ROWS / 128, N_NEU / 128), dim3(256), 0, stream>>>(
            S, PbT, out, B_ROWS, N_NEU, N_PAT);
    }
  }
}